// Round 1
// baseline (818.017 us; speedup 1.0000x reference)
//
#include <hip/hip_runtime.h>
#include <hip/hip_bf16.h>
#include <math.h>

namespace {

constexpr int NA   = 21504;  // anchors (128^2 + 64^2 + 32^2)
constexpr int NB   = 32;     // batch
constexpr int NC   = 80;     // classes
constexpr int BINS = 17;

// ws (double) layout:
// [0,32)    qfl loss sum per batch
// [32,64)   qfl pos count per batch
// [64,96)   dfl ce sum per batch
// [96,128)  mask count (pos) per batch
// [128,160) (1-giou)*mask sum per batch

__device__ __forceinline__ void block_reduce3(float &a, float &b, float &c) {
  #pragma unroll
  for (int off = 32; off > 0; off >>= 1) {
    a += __shfl_down(a, off);
    b += __shfl_down(b, off);
    c += __shfl_down(c, off);
  }
  __shared__ float sa[4], sb[4], sc[4];
  const int wid = threadIdx.x >> 6, lane = threadIdx.x & 63;
  if (lane == 0) { sa[wid] = a; sb[wid] = b; sc[wid] = c; }
  __syncthreads();
  if (threadIdx.x == 0) {
    a = sa[0] + sa[1] + sa[2] + sa[3];
    b = sb[0] + sb[1] + sb[2] + sb[3];
    c = sc[0] + sc[1] + sc[2] + sc[3];
  }
}

__global__ __launch_bounds__(256) void qfl_kernel(const float *__restrict__ pred,
                                                  const float *__restrict__ tgt,
                                                  double *__restrict__ acc) {
  const int b = blockIdx.y;
  const size_t idx = (size_t)b * ((size_t)NA * NC) +
                     (size_t)(blockIdx.x * 256 + threadIdx.x) * 4;
  const float4 p4 = *reinterpret_cast<const float4 *>(pred + idx);
  const float4 t4 = *reinterpret_cast<const float4 *>(tgt + idx);
  float lsum = 0.f, lcnt = 0.f, dummy = 0.f;
  const float ps[4] = {p4.x, p4.y, p4.z, p4.w};
  const float ts[4] = {t4.x, t4.y, t4.z, t4.w};
  #pragma unroll
  for (int c = 0; c < 4; ++c) {
    const float p = ps[c], t = ts[c];
    const float bce = fmaxf(p, 0.f) - p * t + log1pf(__expf(-fabsf(p)));
    const float sig = 1.f / (1.f + __expf(-p));
    const float df = sig - t;
    lsum += bce * df * df;
    lcnt += (t > 0.f) ? 1.f : 0.f;
  }
  block_reduce3(lsum, lcnt, dummy);
  if (threadIdx.x == 0) {
    atomicAdd(&acc[b], (double)lsum);
    atomicAdd(&acc[32 + b], (double)lcnt);
  }
}

__global__ __launch_bounds__(256) void reg_kernel(const float *__restrict__ reg,
                                                  const float *__restrict__ gt,
                                                  const float *__restrict__ anch,
                                                  const float *__restrict__ strides,
                                                  double *__restrict__ acc) {
  const int b = blockIdx.y;
  const int n = blockIdx.x * 256 + threadIdx.x;

  // ---- mask + target distances ----
  const float *g = gt + (size_t)b * 4 * NA + n;
  float tk[4];
  bool fin = false;
  #pragma unroll
  for (int k = 0; k < 4; ++k) {
    const float v = g[(size_t)k * NA];
    fin = fin || !isinf(v);
    tk[k] = v;
  }
  const float mask = fin ? 1.f : 0.f;
  #pragma unroll
  for (int k = 0; k < 4; ++k) tk[k] = fin ? tk[k] : 0.f;

  // ---- per-side log-softmax: DFL ce + expected distance ----
  const float *r = reg + (size_t)b * 4 * BINS * NA + n;
  float ce = 0.f;
  float d[4];
  #pragma unroll
  for (int k = 0; k < 4; ++k) {
    float x[BINS];
    #pragma unroll
    for (int j = 0; j < BINS; ++j) x[j] = r[(size_t)(k * BINS + j) * NA];
    float m = x[0];
    #pragma unroll
    for (int j = 1; j < BINS; ++j) m = fmaxf(m, x[j]);
    float se = 0.f, sj = 0.f;
    #pragma unroll
    for (int j = 0; j < BINS; ++j) {
      const float e = __expf(x[j] - m);
      se += e;
      sj += e * (float)j;
    }
    d[k] = sj / se;                      // softmax expectation
    const float logZ = m + __logf(se);   // log sum exp
    const float t = tk[k];
    const int tl = (int)t;
    const float wr = t - (float)tl, wl = 1.f - wr;
    float xl = 0.f, xr = 0.f;
    #pragma unroll
    for (int j = 0; j < BINS; ++j) {
      xl = (j == tl) ? x[j] : xl;
      xr = (j == tl + 1) ? x[j] : xr;
    }
    ce += (logZ - xl) * wl + (logZ - xr) * wr;
  }
  ce *= mask;

  // ---- GIoU ----
  const float s = strides[n];
  const float2 a2 = reinterpret_cast<const float2 *>(anch)[n];
  const float ax = a2.x, ay = a2.y;
  const float W = 1024.f, H = 1024.f;
  const float px1 = fminf(fmaxf(ax - d[0] * s, 0.f), W);
  const float py1 = fminf(fmaxf(ay - d[1] * s, 0.f), H);
  const float px2 = fminf(fmaxf(ax + d[2] * s, 0.f), W);
  const float py2 = fminf(fmaxf(ay + d[3] * s, 0.f), H);
  const float tx1 = fminf(fmaxf(ax - tk[0] * s, 0.f), W);
  const float ty1 = fminf(fmaxf(ay - tk[1] * s, 0.f), H);
  const float tx2 = fminf(fmaxf(ax + tk[2] * s, 0.f), W);
  const float ty2 = fminf(fmaxf(ay + tk[3] * s, 0.f), H);
  const float iw = fmaxf(fminf(px2, tx2) - fmaxf(px1, tx1), 0.f);
  const float ih = fmaxf(fminf(py2, ty2) - fmaxf(py1, ty1), 0.f);
  const float inter = iw * ih;
  const float area_p = (px2 - px1) * (py2 - py1);
  const float area_t = (tx2 - tx1) * (ty2 - ty1);
  const float uni = area_p + area_t - inter;
  const float iou = inter / fmaxf(uni, 1e-9f);
  const float cw = fmaxf(px2, tx2) - fminf(px1, tx1);
  const float ch = fmaxf(py2, ty2) - fminf(py1, ty1);
  const float area_c = cw * ch;
  const float giou = iou - (area_c - uni) / fmaxf(area_c, 1e-9f);
  float gterm = (1.f - giou) * mask;
  float msk = mask;

  block_reduce3(ce, gterm, msk);
  if (threadIdx.x == 0) {
    atomicAdd(&acc[64 + b], (double)ce);
    atomicAdd(&acc[128 + b], (double)gterm);
    atomicAdd(&acc[96 + b], (double)msk);
  }
}

__global__ void finalize_kernel(const double *__restrict__ acc,
                                float *__restrict__ out) {
  if (threadIdx.x == 0) {
    double qfl = 0., dfl = 0., gio = 0.;
    for (int b = 0; b < NB; ++b) {
      qfl += acc[b] / (acc[32 + b] + 0.001);
      dfl += acc[64 + b] / (4.0 * acc[96 + b] + 0.001);
      const double pos = acc[96 + b];
      double per = acc[128 + b] / fmax(pos, 1.0);
      if (pos == 0.0) per = 0.0;
      gio += per;
    }
    out[0] = (float)(qfl / (double)NB);
    out[1] = (float)(dfl / (double)NB);
    out[2] = (float)(gio / (double)NB);
  }
}

} // namespace

extern "C" void kernel_launch(void *const *d_in, const int *in_sizes, int n_in,
                              void *d_out, int out_size, void *d_ws, size_t ws_size,
                              hipStream_t stream) {
  const float *gt_qfl  = (const float *)d_in[0];  // (B, N, C)
  const float *gt_dfl  = (const float *)d_in[1];  // (B, 4, N)
  const float *anch    = (const float *)d_in[2];  // (N, 2)
  const float *strides = (const float *)d_in[3];  // (N,)
  const float *p_cls   = (const float *)d_in[4];  // (B, N, C)
  const float *p_reg   = (const float *)d_in[5];  // (B, 4, BINS, N)
  (void)gt_dfl; (void)anch; (void)strides; (void)in_sizes; (void)n_in; (void)out_size; (void)ws_size;

  double *acc = (double *)d_ws;
  hipMemsetAsync(acc, 0, 160 * sizeof(double), stream);

  dim3 gq((NA * NC / 4) / 256, NB);   // 1680 x 32
  qfl_kernel<<<gq, 256, 0, stream>>>(p_cls, gt_qfl, acc);

  dim3 gr(NA / 256, NB);              // 84 x 32
  reg_kernel<<<gr, 256, 0, stream>>>(p_reg, gt_dfl, anch, strides, acc);

  finalize_kernel<<<1, 64, 0, stream>>>(acc, (float *)d_out);
}

// Round 4
// 537.883 us; speedup vs baseline: 1.5208x; 1.5208x over previous
//
#include <hip/hip_runtime.h>
#include <hip/hip_bf16.h>
#include <math.h>

namespace {

constexpr int NA   = 21504;   // anchors (128^2 + 64^2 + 32^2)
constexpr int NA2  = NA / 2;  // float2 count along N
constexpr int NB   = 32;      // batch
constexpr int NC   = 80;      // classes
constexpr int BINS = 17;

constexpr int QFL_XB = 210;   // qfl blocks per batch
constexpr int QFL_IT = 8;     // float4 per thread  (210*256*8 = NA*NC/4)
constexpr int REG_XB = 42;    // reg blocks per batch (42*256 = NA/2)

// ws layout:
//   float[NB*QFL_XB*2]  qfl partials {loss_sum, pos_cnt}   @ float idx 0
//   float[NB*REG_XB*3]  reg partials {ce, gterm, mask}     @ float idx NB*QFL_XB*2
//   double[NB*3]        per-batch {qfl, dfl, giou}         @ byte 131072

constexpr int PQ_F = NB * QFL_XB * 2;   // 13440
constexpr size_t PB_OFF = 131072;

template <int K>
__device__ __forceinline__ void block_reduce(float (&v)[K]) {
  #pragma unroll
  for (int off = 32; off > 0; off >>= 1) {
    #pragma unroll
    for (int i = 0; i < K; ++i) v[i] += __shfl_down(v[i], off);
  }
  __shared__ float s[K][4];
  const int wid = threadIdx.x >> 6, lane = threadIdx.x & 63;
  if (lane == 0) {
    #pragma unroll
    for (int i = 0; i < K; ++i) s[i][wid] = v[i];
  }
  __syncthreads();
  if (threadIdx.x == 0) {
    #pragma unroll
    for (int i = 0; i < K; ++i) v[i] = s[i][0] + s[i][1] + s[i][2] + s[i][3];
  }
}

__global__ __launch_bounds__(256) void qfl_kernel(const float *__restrict__ pred,
                                                  const float *__restrict__ tgt,
                                                  float *__restrict__ part) {
  const int b = blockIdx.y;
  const float4 *p4 = reinterpret_cast<const float4 *>(pred + (size_t)b * NA * NC);
  const float4 *t4 = reinterpret_cast<const float4 *>(tgt + (size_t)b * NA * NC);
  float v[2] = {0.f, 0.f};
  int f = blockIdx.x * 256 + threadIdx.x;
  #pragma unroll
  for (int it = 0; it < QFL_IT; ++it, f += QFL_XB * 256) {
    const float4 pv = p4[f];
    const float4 tv = t4[f];
    const float ps[4] = {pv.x, pv.y, pv.z, pv.w};
    const float ts[4] = {tv.x, tv.y, tv.z, tv.w};
    #pragma unroll
    for (int c = 0; c < 4; ++c) {
      const float p = ps[c], t = ts[c];
      const float e = __expf(-fabsf(p));            // exp(-|p|) <= 1
      const float bce = fmaxf(p, 0.f) - p * t + __logf(1.f + e);
      const float r = __builtin_amdgcn_rcpf(1.f + e);
      const float sig = (p >= 0.f) ? r : e * r;     // sigmoid(p)
      const float df = sig - t;
      v[0] += bce * df * df;
      v[1] += (t > 0.f) ? 1.f : 0.f;
    }
  }
  block_reduce<2>(v);
  if (threadIdx.x == 0) {
    const int o = (b * QFL_XB + blockIdx.x) * 2;
    part[o + 0] = v[0];
    part[o + 1] = v[1];
  }
}

__global__ __launch_bounds__(256) void reg_kernel(const float *__restrict__ reg,
                                                  const float *__restrict__ gt,
                                                  const float *__restrict__ anch,
                                                  const float *__restrict__ strides,
                                                  float *__restrict__ part) {
  const int b = blockIdx.y;
  const int n2 = blockIdx.x * 256 + threadIdx.x;   // float2 index along N

  // ---- targets + mask (2 anchors) ----
  const float2 *g2 = reinterpret_cast<const float2 *>(gt + (size_t)b * 4 * NA);
  float tk[2][4];
  bool fin0 = false, fin1 = false;
  #pragma unroll
  for (int k = 0; k < 4; ++k) {
    const float2 gv = g2[k * NA2 + n2];
    fin0 = fin0 || !isinf(gv.x);
    fin1 = fin1 || !isinf(gv.y);
    tk[0][k] = gv.x;
    tk[1][k] = gv.y;
  }
  const float mask[2] = {fin0 ? 1.f : 0.f, fin1 ? 1.f : 0.f};
  #pragma unroll
  for (int k = 0; k < 4; ++k) {
    tk[0][k] = fin0 ? tk[0][k] : 0.f;
    tk[1][k] = fin1 ? tk[1][k] : 0.f;
  }

  // ---- per-side log-softmax: DFL ce + expected distance ----
  const float2 *r2 = reinterpret_cast<const float2 *>(reg + (size_t)b * 4 * BINS * NA);
  float ce[2] = {0.f, 0.f};
  float d[2][4];
  #pragma unroll
  for (int k = 0; k < 4; ++k) {
    float2 x[BINS];
    #pragma unroll
    for (int j = 0; j < BINS; ++j) x[j] = r2[(size_t)(k * BINS + j) * NA2 + n2];
    #pragma unroll
    for (int a = 0; a < 2; ++a) {
      float m = (a == 0) ? x[0].x : x[0].y;
      #pragma unroll
      for (int j = 1; j < BINS; ++j) m = fmaxf(m, (a == 0) ? x[j].x : x[j].y);
      float se = 0.f, sj = 0.f;
      #pragma unroll
      for (int j = 0; j < BINS; ++j) {
        const float e = __expf(((a == 0) ? x[j].x : x[j].y) - m);
        se += e;
        sj += e * (float)j;
      }
      d[a][k] = sj / se;
      const float logZ = m + __logf(se);
      const float t = tk[a][k];
      const int tl = (int)t;
      const float wr = t - (float)tl, wl = 1.f - wr;
      float xl = 0.f, xr = 0.f;
      #pragma unroll
      for (int j = 0; j < BINS; ++j) {
        const float xv = (a == 0) ? x[j].x : x[j].y;
        xl = (j == tl) ? xv : xl;
        xr = (j == tl + 1) ? xv : xr;
      }
      ce[a] += (logZ - xl) * wl + (logZ - xr) * wr;
    }
  }

  // ---- GIoU (2 anchors) ----
  const float2 sv = reinterpret_cast<const float2 *>(strides)[n2];
  const float4 av = reinterpret_cast<const float4 *>(anch)[n2];
  float gterm[2];
  #pragma unroll
  for (int a = 0; a < 2; ++a) {
    const float s = (a == 0) ? sv.x : sv.y;
    const float ax = (a == 0) ? av.x : av.z;
    const float ay = (a == 0) ? av.y : av.w;
    const float W = 1024.f, H = 1024.f;
    const float px1 = fminf(fmaxf(ax - d[a][0] * s, 0.f), W);
    const float py1 = fminf(fmaxf(ay - d[a][1] * s, 0.f), H);
    const float px2 = fminf(fmaxf(ax + d[a][2] * s, 0.f), W);
    const float py2 = fminf(fmaxf(ay + d[a][3] * s, 0.f), H);
    const float tx1 = fminf(fmaxf(ax - tk[a][0] * s, 0.f), W);
    const float ty1 = fminf(fmaxf(ay - tk[a][1] * s, 0.f), H);
    const float tx2 = fminf(fmaxf(ax + tk[a][2] * s, 0.f), W);
    const float ty2 = fminf(fmaxf(ay + tk[a][3] * s, 0.f), H);
    const float iw = fmaxf(fminf(px2, tx2) - fmaxf(px1, tx1), 0.f);
    const float ih = fmaxf(fminf(py2, ty2) - fmaxf(py1, ty1), 0.f);
    const float inter = iw * ih;
    const float area_p = (px2 - px1) * (py2 - py1);
    const float area_t = (tx2 - tx1) * (ty2 - ty1);
    const float uni = area_p + area_t - inter;
    const float iou = inter / fmaxf(uni, 1e-9f);
    const float cw = fmaxf(px2, tx2) - fminf(px1, tx1);
    const float ch = fmaxf(py2, ty2) - fminf(py1, ty1);
    const float area_c = cw * ch;
    const float giou = iou - (area_c - uni) / fmaxf(area_c, 1e-9f);
    gterm[a] = (1.f - giou) * mask[a];
  }

  float v[3];
  v[0] = ce[0] * mask[0] + ce[1] * mask[1];
  v[1] = gterm[0] + gterm[1];
  v[2] = mask[0] + mask[1];
  block_reduce<3>(v);
  if (threadIdx.x == 0) {
    const int o = (b * REG_XB + blockIdx.x) * 3;
    part[o + 0] = v[0];
    part[o + 1] = v[1];
    part[o + 2] = v[2];
  }
}

__global__ __launch_bounds__(256) void finalize1(const float *__restrict__ pq,
                                                 const float *__restrict__ pr,
                                                 double *__restrict__ pb) {
  const int b = blockIdx.x;
  float v[5] = {0.f, 0.f, 0.f, 0.f, 0.f};
  for (int i = threadIdx.x; i < QFL_XB; i += 256) {
    v[0] += pq[(b * QFL_XB + i) * 2 + 0];
    v[1] += pq[(b * QFL_XB + i) * 2 + 1];
  }
  for (int i = threadIdx.x; i < REG_XB; i += 256) {
    v[2] += pr[(b * REG_XB + i) * 3 + 0];   // ce
    v[3] += pr[(b * REG_XB + i) * 3 + 1];   // gterm
    v[4] += pr[(b * REG_XB + i) * 3 + 2];   // mask count
  }
  block_reduce<5>(v);
  if (threadIdx.x == 0) {
    const double lsum = v[0], lcnt = v[1], ce = v[2], gs = v[3], msk = v[4];
    pb[b * 3 + 0] = lsum / (lcnt + 0.001);
    pb[b * 3 + 1] = ce / (4.0 * msk + 0.001);
    pb[b * 3 + 2] = (msk == 0.0) ? 0.0 : gs / fmax(msk, 1.0);
  }
}

__global__ void finalize2(const double *__restrict__ pb, float *__restrict__ out) {
  if (threadIdx.x == 0) {
    double q = 0., d = 0., g = 0.;
    for (int b = 0; b < NB; ++b) {
      q += pb[b * 3 + 0];
      d += pb[b * 3 + 1];
      g += pb[b * 3 + 2];
    }
    out[0] = (float)(q / (double)NB);
    out[1] = (float)(d / (double)NB);
    out[2] = (float)(g / (double)NB);
  }
}

} // namespace

extern "C" void kernel_launch(void *const *d_in, const int *in_sizes, int n_in,
                              void *d_out, int out_size, void *d_ws, size_t ws_size,
                              hipStream_t stream) {
  const float *gt_qfl  = (const float *)d_in[0];  // (B, N, C)
  const float *gt_dfl  = (const float *)d_in[1];  // (B, 4, N)
  const float *anch    = (const float *)d_in[2];  // (N, 2)
  const float *strides = (const float *)d_in[3];  // (N,)
  const float *p_cls   = (const float *)d_in[4];  // (B, N, C)
  const float *p_reg   = (const float *)d_in[5];  // (B, 4, BINS, N)
  (void)in_sizes; (void)n_in; (void)out_size; (void)ws_size;

  float *pq = (float *)d_ws;
  float *pr = pq + PQ_F;
  double *pb = (double *)((char *)d_ws + PB_OFF);

  dim3 gq(QFL_XB, NB);
  qfl_kernel<<<gq, 256, 0, stream>>>(p_cls, gt_qfl, pq);

  dim3 gr(REG_XB, NB);
  reg_kernel<<<gr, 256, 0, stream>>>(p_reg, gt_dfl, anch, strides, pr);

  finalize1<<<NB, 256, 0, stream>>>(pq, pr, pb);
  finalize2<<<1, 64, 0, stream>>>(pb, (float *)d_out);
}